// Round 16
// baseline (112.347 us; speedup 1.0000x reference)
//
#include <hip/hip_runtime.h>

typedef __bf16 bf16x8 __attribute__((ext_vector_type(8)));
typedef float f32x4 __attribute__((ext_vector_type(4)));

#define TWO_LOG2E 2.88539008177792681f   // 2*log2(e): exp(2x) = exp2(x*TWO_LOG2E)

__device__ __forceinline__ unsigned f2bf(float f) {
    unsigned u = __float_as_uint(f);
    return (u + 0x7FFFu + ((u >> 16) & 1u)) >> 16;   // RNE
}

// Blocked layout znB: panel (c16, ks) = 16 cols x 32 k, contiguous 512 elems (1KB).
//   element (row, k): znB[(row>>4)*4096 + (k>>5)*512 + (row&15)*32 + ((k>>3)&3)*8 + (k&7)]
// A wave's MFMA fragment for (c16, ks) = lanes' 8-elem chunks at ((n16<<2)|q)*8 within
// the panel -> ONE fully-coalesced 1KB load per fragment. No LDS anywhere in simexp.

// ---------------- kernel 1: normalize -> row-major zn AND blocked znB -------------------
// Blocks 0..31 also zero S[8192]; block 32 zeroes out[0].
__global__ void __launch_bounds__(256) normalize_kernel(
    const float* __restrict__ z1, const float* __restrict__ z2,
    unsigned short* __restrict__ zn, unsigned short* __restrict__ znB,
    float* __restrict__ S, float* __restrict__ out)
{
    if (blockIdx.x < 32) S[(blockIdx.x << 8) + threadIdx.x] = 0.f;
    if (blockIdx.x == 32 && threadIdx.x == 0) out[0] = 0.f;

    const int wave = threadIdx.x >> 6, lane = threadIdx.x & 63;
    const int row = (blockIdx.x << 2) + wave;               // 2048 blocks * 4 rows
    const float* src = (row < 4096) ? (z1 + row * 256) : (z2 + (row - 4096) * 256);
    float4 v = ((const float4*)src)[lane];                  // 64 lanes * 4 = 256
    float ss = v.x * v.x + v.y * v.y + v.z * v.z + v.w * v.w;
#pragma unroll
    for (int m = 32; m > 0; m >>= 1) ss += __shfl_xor(ss, m, 64);
    float sc = 1.0f / fmaxf(sqrtf(ss), 1e-8f);
    uint2 w;
    w.x = f2bf(v.x * sc) | (f2bf(v.y * sc) << 16);
    w.y = f2bf(v.z * sc) | (f2bf(v.w * sc) << 16);
    // row-major (finish kernel)
    *(uint2*)(zn + row * 256 + (lane << 2)) = w;
    // blocked (simexp fragments): k = 4*lane -> ks=lane>>3, q=(lane>>1)&3, off=(lane&1)*4
    *(uint2*)(znB + ((row >> 4) << 12) + ((lane >> 3) << 9) + ((row & 15) << 5)
                  + (((lane >> 1) & 3) << 3) + ((lane & 1) << 2)) = w;
}

// ---------------- kernel 2: LDS-free sim-exp from blocked layout ------------------------
// Block = ONE wave; 2048 jobs = 128 row-strips(64) x 16 col-runs(512). A = 64 rows x
// K=256 in regs (32 coalesced 1KB loads). Per col-group (16 cols): 8 coalesced 1KB
// B-fragment loads -> 32 MFMA -> 16 exp into register row-sums. All loads are plain
// global->VGPR; the compiler software-pipelines with fine-grained vmcnt (m93/m97
// pattern). No LDS, no barriers, no inline asm. One atomic flush per job.
// XCD locality: run = job&15; blockIdx%8 round-robin => all blocks with run r sit on
// XCD r%8, whose L2 holds just 2 runs' B panels (512KB) -> L2-resident streaming.
__global__ void __launch_bounds__(64, 2) simexp_kernel(
    const unsigned short* __restrict__ znB, float* __restrict__ S)
{
    const int lane = threadIdx.x;
    const int q = lane >> 4, n16 = lane & 15;
    const int lp = (((n16 << 2) | q) << 3);     // lane's element offset within a panel
    const int job = blockIdx.x;                 // 0..2047
    const int rowBase = (job >> 4) << 6;        // strip * 64
    const int run = job & 15;

    // A: 64 rows x K=256 (a[rt][ks] <- panel ((rowBase>>4)+rt, ks))
    bf16x8 a[4][8];
#pragma unroll
    for (int rt = 0; rt < 4; ++rt)
#pragma unroll
        for (int ks = 0; ks < 8; ++ks)
            a[rt][ks] = *(const bf16x8*)(znB + ((((rowBase >> 4) + rt)) << 12)
                                             + (ks << 9) + lp);

    float rs[4][4];
#pragma unroll
    for (int i = 0; i < 4; ++i)
#pragma unroll
        for (int j = 0; j < 4; ++j) rs[i][j] = 0.f;

    const unsigned short* bbase = znB + ((run << 5) << 12);   // run's 32 col-groups

#pragma unroll 2
    for (int cg = 0; cg < 32; ++cg) {           // 16 cols per group
        const unsigned short* gb = bbase + (cg << 12);
        bf16x8 b[8];
#pragma unroll
        for (int ks = 0; ks < 8; ++ks)
            b[ks] = *(const bf16x8*)(gb + (ks << 9) + lp);

        f32x4 acc[4];
#pragma unroll
        for (int rt = 0; rt < 4; ++rt) acc[rt] = (f32x4){0.f, 0.f, 0.f, 0.f};
#pragma unroll
        for (int ks = 0; ks < 8; ++ks)
#pragma unroll
            for (int rt = 0; rt < 4; ++rt)
                acc[rt] = __builtin_amdgcn_mfma_f32_16x16x32_bf16(
                    a[rt][ks], b[ks], acc[rt], 0, 0, 0);

#pragma unroll
        for (int rt = 0; rt < 4; ++rt)
#pragma unroll
            for (int r = 0; r < 4; ++r)
                rs[rt][r] += __builtin_amdgcn_exp2f(acc[rt][r] * TWO_LOG2E);
    }

    // flush once per job (C/D layout: col=n16, row=q*4+r)
#pragma unroll
    for (int rt = 0; rt < 4; ++rt)
#pragma unroll
        for (int r = 0; r < 4; ++r) {
            float s = rs[rt][r];
            s += __shfl_xor(s, 1, 64);
            s += __shfl_xor(s, 2, 64);
            s += __shfl_xor(s, 4, 64);
            s += __shfl_xor(s, 8, 64);
            if (n16 == 0) atomicAdd(&S[rowBase + (rt << 4) + (q << 2) + r], s);
        }
}

// ---------------- kernel 3: loss = mean( log(S_i - e^{sim_ii}) - sim_{i,target} ) -------
__global__ void __launch_bounds__(256) finish_kernel(
    const unsigned short* __restrict__ zn, const float* __restrict__ S,
    float* __restrict__ out)
{
    __shared__ float vals[16];
    const int tid = threadIdx.x, lane = tid & 63, wave = tid >> 6;
    const int q = lane >> 4, n16 = lane & 15;
    const int rib = (wave << 2) + q;                // 0..15 rows per block
    const int row = (blockIdx.x << 4) + rib;        // 512 blocks * 16 rows
    const int tar = (row + 4096) & 8191;

    float drr = 0.f, drt = 0.f;
#pragma unroll
    for (int i = 0; i < 4; ++i) {
        int k = (i << 6) + (n16 << 2);
        uint2 ur = *(const uint2*)(zn + (row << 8) + k);
        uint2 ut = *(const uint2*)(zn + (tar << 8) + k);
        float a0 = __uint_as_float(ur.x << 16),  a1 = __uint_as_float(ur.x & 0xFFFF0000u);
        float a2 = __uint_as_float(ur.y << 16),  a3 = __uint_as_float(ur.y & 0xFFFF0000u);
        float b0 = __uint_as_float(ut.x << 16),  b1 = __uint_as_float(ut.x & 0xFFFF0000u);
        float b2 = __uint_as_float(ut.y << 16),  b3 = __uint_as_float(ut.y & 0xFFFF0000u);
        drr += a0 * a0 + a1 * a1 + a2 * a2 + a3 * a3;
        drt += a0 * b0 + a1 * b1 + a2 * b2 + a3 * b3;
    }
#pragma unroll
    for (int m = 1; m <= 8; m <<= 1) {
        drr += __shfl_xor(drr, m, 64);
        drt += __shfl_xor(drt, m, 64);
    }
    if (n16 == 0) {
        float Sv = S[row] - __builtin_amdgcn_exp2f(drr * TWO_LOG2E);  // remove diagonal
        vals[rib] = 0.693147180559945f * __builtin_amdgcn_logf(Sv) - 2.0f * drt;
    }
    __syncthreads();
    if (tid == 0) {
        float s = 0.f;
#pragma unroll
        for (int i = 0; i < 16; ++i) s += vals[i];
        atomicAdd(out, s * (1.0f / 8192.0f));
    }
}

extern "C" void kernel_launch(void* const* d_in, const int* in_sizes, int n_in,
                              void* d_out, int out_size, void* d_ws, size_t ws_size,
                              hipStream_t stream)
{
    const float* z1 = (const float*)d_in[0];
    const float* z2 = (const float*)d_in[1];
    unsigned short* zn  = (unsigned short*)d_ws;                       // 4 MB row-major
    unsigned short* znB = zn + 8192 * 256;                             // 4 MB blocked
    float* S = (float*)((char*)d_ws + 2 * 8192 * 256 * sizeof(unsigned short)); // 32 KB
    float* out = (float*)d_out;

    normalize_kernel<<<2048, 256, 0, stream>>>(z1, z2, zn, znB, S, out);
    simexp_kernel<<<2048, 64, 0, stream>>>(znB, S);
    finish_kernel<<<512, 256, 0, stream>>>(zn, S, out);
}

// Round 17
// 105.814 us; speedup vs baseline: 1.0617x; 1.0617x over previous
//
#include <hip/hip_runtime.h>
#include <hip/hip_cooperative_groups.h>

namespace cg = cooperative_groups;

typedef __bf16 bf16x8 __attribute__((ext_vector_type(8)));
typedef float f32x4 __attribute__((ext_vector_type(4)));

#define TWO_LOG2E 2.88539008177792681f   // 2*log2(e): exp(2x) = exp2(x*TWO_LOG2E)

#define GLOADLDS16(g, l) __builtin_amdgcn_global_load_lds(                     \
    (const __attribute__((address_space(1))) void*)(g),                        \
    (__attribute__((address_space(3))) void*)(l), 16, 0, 0)

__device__ __forceinline__ unsigned f2bf(float f) {
    unsigned u = __float_as_uint(f);
    return (u + 0x7FFFu + ((u >> 16) & 1u)) >> 16;   // RNE
}

// ============ phase 2 core (R15-proven, 42.9us): one wave, one job, private LDS =========
// job = strip(64 rows) x run(512 cols). A = 64x256 in regs. B streams through a
// wave-private ring of FOUR 2KB LDS buffers via global_load_lds; steady-state
// `s_waitcnt vmcnt(6)` (3 stages in flight) orders DMA->ds_read (compiler does NOT
// model it — R9 NaN); peeled tail drains 6->4->2->0. No __syncthreads in this phase.
__device__ __forceinline__ void simexp_wave(const unsigned short* __restrict__ zn,
                                            float* __restrict__ S,
                                            unsigned short* __restrict__ ring, // 4x1024
                                            int job, int lane)
{
    const int q = lane >> 4, n16 = lane & 15;
    const int rowBase = (job >> 4) << 6;        // strip * 64
    const int colRun  = (job & 15) << 9;        // run * 512

    bf16x8 a[4][8];
#pragma unroll
    for (int rt = 0; rt < 4; ++rt)
#pragma unroll
        for (int ks = 0; ks < 8; ++ks)
            a[rt][ks] = *(const bf16x8*)(zn + ((rowBase + (rt << 4) + n16) << 8)
                                            + (ks << 5) + (q << 3));

    auto stage = [&](int m) {
        const int colBase = colRun + ((m >> 3) << 5);
        const int koff = (m & 7) << 5;          // elems
        unsigned short* base = ring + ((m & 3) << 10);
#pragma unroll
        for (int p = 0; p < 2; ++p) {
            int s = (p << 6) + lane;            // 16B slot 0..127
            int c = s >> 2, d = s & 3;
            int k8 = d ^ (c & 3);               // XOR swizzle
            GLOADLDS16(zn + ((colBase + c) << 8) + koff + (k8 << 3), base + (s << 3));
        }
    };

    float rs[4][4];
#pragma unroll
    for (int i = 0; i < 4; ++i)
#pragma unroll
        for (int j = 0; j < 4; ++j) rs[i][j] = 0.f;

    f32x4 acc[4][2];
    auto consume = [&](int m) {
        const unsigned short* bb = ring + ((m & 3) << 10);
        const int kc = m & 7;
        bf16x8 bf[2];
#pragma unroll
        for (int ct = 0; ct < 2; ++ct) {
            int c = (ct << 4) + n16;
            int d = q ^ (c & 3);
            bf[ct] = *(const bf16x8*)(bb + (((c << 2) | d) << 3));
        }
#pragma unroll
        for (int rt = 0; rt < 4; ++rt)
#pragma unroll
            for (int ct = 0; ct < 2; ++ct)
                acc[rt][ct] = __builtin_amdgcn_mfma_f32_16x16x32_bf16(
                    a[rt][kc], bf[ct], acc[rt][ct], 0, 0, 0);
    };
    auto acczero = [&]() {
#pragma unroll
        for (int rt = 0; rt < 4; ++rt)
#pragma unroll
            for (int ct = 0; ct < 2; ++ct) acc[rt][ct] = (f32x4){0.f, 0.f, 0.f, 0.f};
    };
    auto epilogue = [&]() {
#pragma unroll
        for (int rt = 0; rt < 4; ++rt)
#pragma unroll
            for (int ct = 0; ct < 2; ++ct)
#pragma unroll
                for (int r = 0; r < 4; ++r)
                    rs[rt][r] += __builtin_amdgcn_exp2f(acc[rt][ct][r] * TWO_LOG2E);
    };

    stage(0); stage(1); stage(2);

    for (int cc = 0; cc < 15; ++cc) {
        acczero();
#pragma unroll
        for (int kc = 0; kc < 8; ++kc) {
            int m = (cc << 3) + kc;
            stage(m + 3);
            asm volatile("s_waitcnt vmcnt(6)" ::: "memory");
            consume(m);
        }
        epilogue();
    }
    acczero();
#pragma unroll
    for (int kc = 0; kc < 5; ++kc) {
        int m = 120 + kc;
        stage(m + 3);
        asm volatile("s_waitcnt vmcnt(6)" ::: "memory");
        consume(m);
    }
    asm volatile("s_waitcnt vmcnt(4)" ::: "memory");
    consume(125);
    asm volatile("s_waitcnt vmcnt(2)" ::: "memory");
    consume(126);
    asm volatile("s_waitcnt vmcnt(0)" ::: "memory");
    consume(127);
    epilogue();

#pragma unroll
    for (int rt = 0; rt < 4; ++rt)
#pragma unroll
        for (int r = 0; r < 4; ++r) {
            float s = rs[rt][r];
            s += __shfl_xor(s, 1, 64);
            s += __shfl_xor(s, 2, 64);
            s += __shfl_xor(s, 4, 64);
            s += __shfl_xor(s, 8, 64);
            if (n16 == 0) atomicAdd(&S[rowBase + (rt << 4) + (q << 2) + r], s);
        }
}

// ================= fused cooperative kernel: 512 blocks x 256 threads ===================
__global__ void __launch_bounds__(256, 2) ntxent_fused(
    const float* __restrict__ z1, const float* __restrict__ z2,
    unsigned short* __restrict__ zn, float* __restrict__ S, float* __restrict__ out)
{
    __shared__ __align__(16) unsigned short Bs[4][4][1024];   // 8 KB ring per wave

    const int tid = threadIdx.x, lane = tid & 63, wave = tid >> 6;
    const int q = lane >> 4, n16 = lane & 15;
    const int b = blockIdx.x;

    // ---- phase 1: normalize 16 rows; zero S (16 each) and out ----
    if (tid < 16) S[(b << 4) + tid] = 0.f;
    if (b == 0 && tid == 0) out[0] = 0.f;
#pragma unroll
    for (int r = 0; r < 4; ++r) {
        int row = (b << 4) + (wave << 2) + r;
        const float* src = (row < 4096) ? (z1 + row * 256) : (z2 + (row - 4096) * 256);
        float4 v = ((const float4*)src)[lane];
        float ss = v.x * v.x + v.y * v.y + v.z * v.z + v.w * v.w;
#pragma unroll
        for (int m = 32; m > 0; m >>= 1) ss += __shfl_xor(ss, m, 64);
        float sc = 1.0f / fmaxf(sqrtf(ss), 1e-8f);
        uint2 w;
        w.x = f2bf(v.x * sc) | (f2bf(v.y * sc) << 16);
        w.y = f2bf(v.z * sc) | (f2bf(v.w * sc) << 16);
        *(uint2*)(zn + row * 256 + (lane << 2)) = w;
    }

    cg::this_grid().sync();

    // ---- phase 2: one R15 job per wave (512 blocks x 4 waves = 2048 jobs) ----
    simexp_wave(zn, S, &Bs[wave][0][0], (b << 2) | wave, lane);

    cg::this_grid().sync();

    // ---- phase 3: loss for this block's 16 rows ----
    float* vals = (float*)&Bs[0][0][0];
    const int rib = (wave << 2) + q;
    const int row = (b << 4) + rib;
    const int tar = (row + 4096) & 8191;
    float drr = 0.f, drt = 0.f;
#pragma unroll
    for (int i = 0; i < 4; ++i) {
        int k = (i << 6) + (n16 << 2);
        uint2 ur = *(const uint2*)(zn + (row << 8) + k);
        uint2 ut = *(const uint2*)(zn + (tar << 8) + k);
        float a0 = __uint_as_float(ur.x << 16),  a1 = __uint_as_float(ur.x & 0xFFFF0000u);
        float a2 = __uint_as_float(ur.y << 16),  a3 = __uint_as_float(ur.y & 0xFFFF0000u);
        float b0 = __uint_as_float(ut.x << 16),  b1 = __uint_as_float(ut.x & 0xFFFF0000u);
        float b2 = __uint_as_float(ut.y << 16),  b3 = __uint_as_float(ut.y & 0xFFFF0000u);
        drr += a0 * a0 + a1 * a1 + a2 * a2 + a3 * a3;
        drt += a0 * b0 + a1 * b1 + a2 * b2 + a3 * b3;
    }
#pragma unroll
    for (int m = 1; m <= 8; m <<= 1) {
        drr += __shfl_xor(drr, m, 64);
        drt += __shfl_xor(drt, m, 64);
    }
    __syncthreads();                             // Bs (ring) reuse as vals is safe now
    if (n16 == 0) {
        float Sv = S[row] - __builtin_amdgcn_exp2f(drr * TWO_LOG2E);
        vals[rib] = 0.693147180559945f * __builtin_amdgcn_logf(Sv) - 2.0f * drt;
    }
    __syncthreads();
    if (tid == 0) {
        float s = 0.f;
#pragma unroll
        for (int i = 0; i < 16; ++i) s += vals[i];
        atomicAdd(out, s * (1.0f / 8192.0f));
    }
}

// ================= fallback kernels (R15-proven 3-dispatch pipeline) ====================
__global__ void __launch_bounds__(256) normalize_kernel(
    const float* __restrict__ z1, const float* __restrict__ z2,
    unsigned short* __restrict__ zn, float* __restrict__ S, float* __restrict__ out)
{
    if (blockIdx.x < 32) S[(blockIdx.x << 8) + threadIdx.x] = 0.f;
    if (blockIdx.x == 32 && threadIdx.x == 0) out[0] = 0.f;
    const int wave = threadIdx.x >> 6, lane = threadIdx.x & 63;
    const int row = (blockIdx.x << 2) + wave;
    const float* src = (row < 4096) ? (z1 + row * 256) : (z2 + (row - 4096) * 256);
    float4 v = ((const float4*)src)[lane];
    float ss = v.x * v.x + v.y * v.y + v.z * v.z + v.w * v.w;
#pragma unroll
    for (int m = 32; m > 0; m >>= 1) ss += __shfl_xor(ss, m, 64);
    float sc = 1.0f / fmaxf(sqrtf(ss), 1e-8f);
    uint2 w;
    w.x = f2bf(v.x * sc) | (f2bf(v.y * sc) << 16);
    w.y = f2bf(v.z * sc) | (f2bf(v.w * sc) << 16);
    *(uint2*)(zn + row * 256 + (lane << 2)) = w;
}

__global__ void __launch_bounds__(64, 2) simexp_kernel(
    const unsigned short* __restrict__ zn, float* __restrict__ S)
{
    __shared__ __align__(16) unsigned short Bs[4][1024];
    simexp_wave(zn, S, &Bs[0][0], blockIdx.x, threadIdx.x);
}

__global__ void __launch_bounds__(256) finish_kernel(
    const unsigned short* __restrict__ zn, const float* __restrict__ S,
    float* __restrict__ out)
{
    __shared__ float vals[16];
    const int tid = threadIdx.x, lane = tid & 63, wave = tid >> 6;
    const int q = lane >> 4, n16 = lane & 15;
    const int rib = (wave << 2) + q;
    const int row = (blockIdx.x << 4) + rib;
    const int tar = (row + 4096) & 8191;
    float drr = 0.f, drt = 0.f;
#pragma unroll
    for (int i = 0; i < 4; ++i) {
        int k = (i << 6) + (n16 << 2);
        uint2 ur = *(const uint2*)(zn + (row << 8) + k);
        uint2 ut = *(const uint2*)(zn + (tar << 8) + k);
        float a0 = __uint_as_float(ur.x << 16),  a1 = __uint_as_float(ur.x & 0xFFFF0000u);
        float a2 = __uint_as_float(ur.y << 16),  a3 = __uint_as_float(ur.y & 0xFFFF0000u);
        float b0 = __uint_as_float(ut.x << 16),  b1 = __uint_as_float(ut.x & 0xFFFF0000u);
        float b2 = __uint_as_float(ut.y << 16),  b3 = __uint_as_float(ut.y & 0xFFFF0000u);
        drr += a0 * a0 + a1 * a1 + a2 * a2 + a3 * a3;
        drt += a0 * b0 + a1 * b1 + a2 * b2 + a3 * b3;
    }
#pragma unroll
    for (int m = 1; m <= 8; m <<= 1) {
        drr += __shfl_xor(drr, m, 64);
        drt += __shfl_xor(drt, m, 64);
    }
    if (n16 == 0) {
        float Sv = S[row] - __builtin_amdgcn_exp2f(drr * TWO_LOG2E);
        vals[rib] = 0.693147180559945f * __builtin_amdgcn_logf(Sv) - 2.0f * drt;
    }
    __syncthreads();
    if (tid == 0) {
        float s = 0.f;
#pragma unroll
        for (int i = 0; i < 16; ++i) s += vals[i];
        atomicAdd(out, s * (1.0f / 8192.0f));
    }
}

extern "C" void kernel_launch(void* const* d_in, const int* in_sizes, int n_in,
                              void* d_out, int out_size, void* d_ws, size_t ws_size,
                              hipStream_t stream)
{
    const float* z1 = (const float*)d_in[0];
    const float* z2 = (const float*)d_in[1];
    unsigned short* zn = (unsigned short*)d_ws;                              // 4 MB
    float* S = (float*)((char*)d_ws + 8192 * 256 * sizeof(unsigned short));  // 32 KB
    float* out = (float*)d_out;

    // Host-only queries (graph-capture safe): need all 512 blocks co-resident.
    int dev = 0;
    hipGetDevice(&dev);
    int coopOK = 0;
    hipDeviceGetAttribute(&coopOK, hipDeviceAttributeCooperativeLaunch, dev);
    int cus = 0;
    hipDeviceGetAttribute(&cus, hipDeviceAttributeMultiprocessorCount, dev);
    int maxB = 0;
    hipOccupancyMaxActiveBlocksPerMultiprocessor(&maxB, ntxent_fused, 256, 0);

    if (coopOK && (long long)maxB * cus >= 512) {
        void* args[] = {(void*)&z1, (void*)&z2, (void*)&zn, (void*)&S, (void*)&out};
        hipError_t err = hipLaunchCooperativeKernel(ntxent_fused, dim3(512), dim3(256),
                                                    args, 0, stream);
        if (err == hipSuccess) return;
    }
    // Fallback: R15-proven 3-kernel pipeline (~105 us).
    normalize_kernel<<<2048, 256, 0, stream>>>(z1, z2, zn, S, out);
    simexp_kernel<<<2048, 64, 0, stream>>>(zn, S);
    finish_kernel<<<512, 256, 0, stream>>>(zn, S, out);
}